// Round 6
// baseline (1417.418 us; speedup 1.0000x reference)
//
#include <hip/hip_runtime.h>
#include <hip/hip_bf16.h>

// Problem constants
#define BB 4
#define TT 2048
#define DD 1024
#define HH 16
#define SS 64
#define CH 64
#define NC (TT/CH)        // 32
#define M_ROWS (BB*TT)    // 8192

typedef __hip_bfloat16 bf16;
using short8 = __attribute__((ext_vector_type(8))) short;   // 8 bf16 (4 VGPRs)
using f32x4  = __attribute__((ext_vector_type(4))) float;

static __device__ __forceinline__ float b2f(bf16 v) { return __bfloat162float(v); }

// ---- block-wide sum over 256 threads (deterministic tree) ----
static __device__ __forceinline__ float block_sum(float v, float* red) {
  int tid = threadIdx.x;
  red[tid] = v; __syncthreads();
  #pragma unroll
  for (int o = 128; o > 0; o >>= 1) {
    if (tid < o) red[tid] += red[tid + o];
    __syncthreads();
  }
  float r = red[0];
  __syncthreads();
  return r;
}

// ---- K1a: weight-scale partials. grid (5,64) ----
__global__ __launch_bounds__(256) void k_wscale_part(const float* __restrict__ w,
                                                     double* __restrict__ wpart) {
  __shared__ double red[256];
  int i = blockIdx.x, b = blockIdx.y, tid = threadIdx.x;
  const float* base = w + (size_t)i * DD * DD + (size_t)b * 16384;
  double s = 0.0;
  #pragma unroll
  for (int j = 0; j < 64; j++) s += (double)fabsf(base[tid + j * 256]);
  red[tid] = s; __syncthreads();
  for (int o = 128; o > 0; o >>= 1) {
    if (tid < o) red[tid] += red[tid + o];
    __syncthreads();
  }
  if (tid == 0) wpart[i * 64 + b] = red[0];
}

// ---- K1b: fold 64 partials per matrix in fixed order ----
__global__ __launch_bounds__(64) void k_wscale_fin(const double* __restrict__ wpart,
                                                   float* __restrict__ wscale) {
  int i = blockIdx.x;
  if (threadIdx.x == 0) {
    double s = 0.0;
    for (int b = 0; b < 64; b++) s += wpart[i * 64 + b];
    wscale[i] = fmaxf((float)(s * (1.0 / (DD * DD))), 1e-8f);
  }
}

// ---- K2: ternary weight quant, stored as exact bf16 {-1,0,1} ----
__global__ __launch_bounds__(256) void k_wquant(const float* __restrict__ w,
                                                const float* __restrict__ wscale,
                                                bf16* __restrict__ wq) {
  int idx = blockIdx.x * 256 + threadIdx.x;   // < 5*1024*1024
  int i = idx >> 20;
  float ws = wscale[i];
  float wn = w[idx] / ws;
  wn = fminf(fmaxf(wn, -1.f), 1.f);
  wq[idx] = __float2bfloat16(rintf(wn));
}

// ---- K3: token-shift mix + LayerNorm + activation quant ----
__global__ __launch_bounds__(256) void k_prep_quant(
    const float* __restrict__ x, const float* __restrict__ mu_r,
    const float* __restrict__ mu_k, const float* __restrict__ mu_v,
    const float* __restrict__ mu_g, const float* __restrict__ ln_g,
    const float* __restrict__ ln_b, bf16* __restrict__ xq,
    float* __restrict__ ascale) {
  __shared__ float red[256];
  int m = blockIdx.x, i = blockIdx.y, tid = threadIdx.x;
  int t = m & (TT - 1);
  const float* mu = (i == 0) ? mu_r : (i == 1) ? mu_k : (i == 2) ? mu_v : mu_g;
  const float* xr = x + (size_t)m * DD;
  const float* lg = ln_g + i * DD;
  const float* lb = ln_b + i * DD;
  float inp[4];
  #pragma unroll
  for (int j = 0; j < 4; j++) {
    int d = tid + j * 256;
    float xv = xr[d];
    float xs = (t > 0) ? xr[d - DD] : 0.f;
    inp[j] = xv + (xs - xv) * mu[d];
  }
  float mean = block_sum(inp[0] + inp[1] + inp[2] + inp[3], red) * (1.f / DD);
  float var = 0.f;
  #pragma unroll
  for (int j = 0; j < 4; j++) { float dv = inp[j] - mean; var += dv * dv; }
  var = block_sum(var, red) * (1.f / DD);
  float rstd = 1.f / sqrtf(var + 1e-5f);
  float ln[4]; float aabs = 0.f;
  #pragma unroll
  for (int j = 0; j < 4; j++) {
    int d = tid + j * 256;
    ln[j] = (inp[j] - mean) * rstd * lg[d] + lb[d];
    aabs += fabsf(ln[j]);
  }
  float meanabs = block_sum(aabs, red) * (1.f / DD);
  float scale = fmaxf(meanabs, 1e-8f) * 2.5f * (1.f / 127.f);
  bf16* xo = xq + ((size_t)i * M_ROWS + m) * DD;
  #pragma unroll
  for (int j = 0; j < 4; j++) {
    int d = tid + j * 256;
    float q = rintf(fminf(fmaxf(ln[j] / scale, -127.f), 127.f));
    xo[d] = __float2bfloat16(q);              // exact: |int| <= 127
  }
  if (tid == 0) ascale[i * M_ROWS + m] = scale;
}

// ---- K4/K9: bf16 MFMA GEMM, 128x128 tile (m93 ladder step).
// 4 waves in 2x2; each wave 64x64 = 4x4 MFMA tiles, mfma_f32_16x16x32_bf16.
// Fragment conventions identical to the 64x64 version validated bit-exact
// vs VALU in R2/R3. LDS rows padded to 40 shorts: frag ds_read_b128 2-way. ----
__global__ __launch_bounds__(256) void k_gemm(
    const bf16* __restrict__ Axq, const bf16* __restrict__ Wq,
    const float* __restrict__ ascale, const float* __restrict__ wscale,
    int projbase, float* __restrict__ outF) {
  __shared__ short As[128][40];
  __shared__ short Bs[128][40];
  int tid = threadIdx.x;
  int wvid = tid >> 6, lane = tid & 63;
  int wm = wvid >> 1, wn = wvid & 1;
  int m0 = blockIdx.x * 128, n0 = blockIdx.y * 128;
  int z = blockIdx.z;
  int proj = projbase + z;
  const bf16* Ap = Axq + ((size_t)z * M_ROWS + m0) * DD;
  const bf16* Wp = Wq + ((size_t)proj * DD + n0) * DD;
  f32x4 acc[4][4];
  #pragma unroll
  for (int i = 0; i < 4; i++)
    #pragma unroll
    for (int j = 0; j < 4; j++) acc[i][j] = (f32x4){0.f, 0.f, 0.f, 0.f};
  int row = tid >> 2, cg = tid & 3;           // staging: 16B/thread, 2 row-passes
  int frow = lane & 15, fq8 = (lane >> 4) * 8;
  for (int k0 = 0; k0 < DD; k0 += 32) {
    #pragma unroll
    for (int rr = 0; rr < 2; rr++) {
      *(uint4*)&As[rr * 64 + row][cg * 8] =
          *(const uint4*)&Ap[(size_t)(rr * 64 + row) * DD + k0 + cg * 8];
      *(uint4*)&Bs[rr * 64 + row][cg * 8] =
          *(const uint4*)&Wp[(size_t)(rr * 64 + row) * DD + k0 + cg * 8];
    }
    __syncthreads();
    short8 af[4], bfr[4];
    #pragma unroll
    for (int i = 0; i < 4; i++)
      af[i] = *(short8*)&As[64 * wm + 16 * i + frow][fq8];
    #pragma unroll
    for (int j = 0; j < 4; j++)
      bfr[j] = *(short8*)&Bs[64 * wn + 16 * j + frow][fq8];
    #pragma unroll
    for (int i = 0; i < 4; i++)
      #pragma unroll
      for (int j = 0; j < 4; j++)
        acc[i][j] = __builtin_amdgcn_mfma_f32_16x16x32_bf16(af[i], bfr[j], acc[i][j], 0, 0, 0);
    __syncthreads();
  }
  const float* asc = ascale + (size_t)z * M_ROWS + m0;
  float wsc = wscale[proj];
  int col = lane & 15, rg = lane >> 4;
  #pragma unroll
  for (int i = 0; i < 4; i++) {
    #pragma unroll
    for (int r = 0; r < 4; r++) {
      int mm = 64 * wm + 16 * i + rg * 4 + r;
      float s = asc[mm] * wsc;
      #pragma unroll
      for (int j = 0; j < 4; j++) {
        int nn = 64 * wn + 16 * j + col;
        outF[((size_t)z * M_ROWS + m0 + mm) * DD + (n0 + nn)] = acc[i][j][r] * s;
      }
    }
  }
}

// ---- K5: per-chunk injection  inj[s,o] = sum_c w^{63-c} k[c,s] v[c,o] ----
__global__ __launch_bounds__(256) void k_inj(const float* __restrict__ rkvg,
                                             const float* __restrict__ log_decay,
                                             float* __restrict__ states) {
  __shared__ float ksh[CH * SS], vsh[CH * SS];
  int blk = blockIdx.x, tid = threadIdx.x;
  int n = blk & (NC - 1), h = (blk >> 5) & (HH - 1), b = blk >> 9;
  size_t rowbase = ((size_t)b * TT + n * CH) * DD + h * SS;
  const float* Kp = rkvg + (size_t)1 * M_ROWS * DD + rowbase;
  const float* Vp = rkvg + (size_t)2 * M_ROWS * DD + rowbase;
  for (int idx = tid; idx < CH * SS; idx += 256) {
    int c = idx >> 6, s2 = idx & 63;
    ksh[idx] = Kp[(size_t)c * DD + s2];
    vsh[idx] = Vp[(size_t)c * DD + s2];
  }
  int o = tid & 63, sg = tid >> 6;
  float wv[16], acc[16];
  #pragma unroll
  for (int j = 0; j < 16; j++) {
    int s2 = sg * 16 + j;
    float e = expf(log_decay[h * SS + s2]);
    wv[j] = expf(-e); acc[j] = 0.f;
  }
  __syncthreads();
  for (int c = 0; c < CH; c++) {
    float vvv = vsh[c * SS + o];
    #pragma unroll
    for (int j = 0; j < 16; j++)
      acc[j] = wv[j] * acc[j] + ksh[c * SS + sg * 16 + j] * vvv;
  }
  float* st = states + (size_t)blk * SS * SS;
  #pragma unroll
  for (int j = 0; j < 16; j++) st[(size_t)(sg * 16 + j) * SS + o] = acc[j];
}

// ---- K6: in-place scan over chunks ----
__global__ __launch_bounds__(256) void k_scan(const float* __restrict__ log_decay,
                                              float* __restrict__ states) {
  int bh = blockIdx.x, tid = threadIdx.x;
  int h = bh & (HH - 1);
  int o = tid & 63, sg = tid >> 6;
  float wC[16], cur[16];
  #pragma unroll
  for (int j = 0; j < 16; j++) {
    int s2 = sg * 16 + j;
    float e = expf(log_decay[h * SS + s2]);
    wC[j] = expf(-64.f * e);
    cur[j] = 0.f;
  }
  float* base = states + (size_t)bh * NC * SS * SS;
  for (int n = 0; n < NC; n++) {
    float* p = base + (size_t)n * SS * SS;
    #pragma unroll
    for (int j = 0; j < 16; j++) {
      size_t ii = (size_t)(sg * 16 + j) * SS + o;
      float inj = p[ii];
      p[ii] = cur[j];
      cur[j] = wC[j] * cur[j] + inj;
    }
  }
}

// ---- K7 v2: barrier-free WKV. lane=o; wave sg owns s-slice [sg*16,+16).
// Pass A backward: a[j]=k*v+w*a, y[t]=sum r*a (+beta*v in wave 0).
// Pass B forward: y[t] += sum r*pw*st, pw*=w.  y[64] fully in VGPRs.
// One cross-wave reduce at the end through reclaimed LDS. 5 barriers total. ----
__global__ __launch_bounds__(256, 2) void k_wkv_y(const float* __restrict__ rkvg,
                                                  const float* __restrict__ log_decay,
                                                  const float* __restrict__ u,
                                                  const float* __restrict__ states,
                                                  float* __restrict__ Y) {
  __shared__ float rsh[CH * SS], ksh[CH * SS], vsh[CH * SS];
  __shared__ float betash[CH], eush[SS];
  int blk = blockIdx.x, tid = threadIdx.x;
  int n = blk & (NC - 1), h = (blk >> 5) & (HH - 1), b = blk >> 9;
  size_t rowbase = ((size_t)b * TT + n * CH) * DD + h * SS;
  const float* Rp = rkvg + rowbase;
  const float* Kp = rkvg + (size_t)1 * M_ROWS * DD + rowbase;
  const float* Vp = rkvg + (size_t)2 * M_ROWS * DD + rowbase;
  for (int idx = tid; idx < CH * SS; idx += 256) {
    int c = idx >> 6, s2 = idx & 63;
    rsh[idx] = Rp[(size_t)c * DD + s2];
    ksh[idx] = Kp[(size_t)c * DD + s2];
    vsh[idx] = Vp[(size_t)c * DD + s2];
  }
  if (tid < SS) eush[tid] = expf(u[h * SS + tid]);
  __syncthreads();
  // beta[t] = sum_s r[t,s]k[t,s]eu[s]; diagonal access -> 2-way banks (free)
  if (tid < CH) {
    float s = 0.f;
    for (int q = 0; q < SS; q++) {
      int s2 = (q + tid) & 63;
      s += rsh[tid * SS + s2] * ksh[tid * SS + s2] * eush[s2];
    }
    betash[tid] = s;
  }
  __syncthreads();

  int o = tid & 63, sg = tid >> 6, S0 = sg * 16;
  float wv[16];
  #pragma unroll
  for (int j = 0; j < 16; j++) wv[j] = expf(-expf(log_decay[h * SS + S0 + j]));

  float y[CH];
  float a[16];
  #pragma unroll
  for (int j = 0; j < 16; j++) a[j] = 0.f;
  // ---- pass A: backward suffix scan, no barriers ----
  #pragma unroll
  for (int ti = 0; ti < CH; ti++) {
    int t = CH - 1 - ti;
    float v = vsh[t * SS + o];
    float p = 0.f;
    #pragma unroll
    for (int q = 0; q < 4; q++) {
      float4 k4 = *(const float4*)&ksh[t * SS + S0 + q * 4];
      float4 r4 = *(const float4*)&rsh[t * SS + S0 + q * 4];
      float kk[4] = {k4.x, k4.y, k4.z, k4.w};
      float rr[4] = {r4.x, r4.y, r4.z, r4.w};
      #pragma unroll
      for (int e = 0; e < 4; e++) {
        int j = q * 4 + e;
        a[j] = fmaf(wv[j], a[j], kk[e] * v);
        p = fmaf(rr[e], a[j], p);
      }
    }
    y[t] = (sg == 0) ? fmaf(betash[t], v, p) : p;
  }
  // ---- pass B: forward cross-chunk term, no barriers ----
  const float* stp = states + (size_t)blk * SS * SS;
  float st[16], pw[16];
  #pragma unroll
  for (int j = 0; j < 16; j++) {
    st[j] = stp[(size_t)(S0 + j) * SS + o];
    pw[j] = wv[j];
  }
  #pragma unroll
  for (int t = 0; t < CH; t++) {
    float p2 = 0.f;
    #pragma unroll
    for (int q = 0; q < 4; q++) {
      float4 r4 = *(const float4*)&rsh[t * SS + S0 + q * 4];
      float rr[4] = {r4.x, r4.y, r4.z, r4.w};
      #pragma unroll
      for (int e = 0; e < 4; e++) {
        int j = q * 4 + e;
        p2 = fmaf(rr[e], pw[j] * st[j], p2);
        pw[j] *= wv[j];
      }
    }
    y[t] += p2;
  }
  __syncthreads();   // everyone done reading rsh/ksh/vsh -> reclaim for reduce
  float* dst = (sg == 0) ? rsh : (sg == 1) ? ksh : vsh;
  if (sg < 3) {
    #pragma unroll
    for (int t = 0; t < CH; t++) dst[t * SS + o] = y[t];
  }
  __syncthreads();
  if (sg == 3) {
    float* Yb = Y + ((size_t)b * TT + n * CH) * DD + h * SS;
    #pragma unroll
    for (int t = 0; t < CH; t++)
      Yb[(size_t)t * DD + o] = y[t] + rsh[t * SS + o] + ksh[t * SS + o] + vsh[t * SS + o];
  }
}

// ---- K8: GroupNorm + silu(g) + LayerNorm + act-quant ----
__global__ __launch_bounds__(256) void k_post(const float* __restrict__ Y,
                                              const float* __restrict__ G,
                                              const float* __restrict__ gn_g,
                                              const float* __restrict__ gn_b,
                                              const float* __restrict__ lg,
                                              const float* __restrict__ lb,
                                              bf16* __restrict__ xq4,
                                              float* __restrict__ ascale4) {
  __shared__ float red[256];
  __shared__ float ysh[DD];
  __shared__ float gmean[HH], grstd[HH];
  int m = blockIdx.x, tid = threadIdx.x;
  const float* Yr = Y + (size_t)m * DD;
  const float* Gr = G + (size_t)m * DD;
  #pragma unroll
  for (int j = 0; j < 4; j++) { int d = tid + j * 256; ysh[d] = Yr[d]; }
  __syncthreads();
  if (tid < HH) {
    float s = 0.f;
    for (int q2 = 0; q2 < SS; q2++) s += ysh[tid * SS + ((q2 + tid * 4) & 63)];
    float mn = s * (1.f / SS);
    float v2 = 0.f;
    for (int q2 = 0; q2 < SS; q2++) {
      float dv = ysh[tid * SS + ((q2 + tid * 4) & 63)] - mn; v2 += dv * dv;
    }
    gmean[tid] = mn;
    grstd[tid] = 1.f / sqrtf(v2 * (1.f / SS) + 1e-5f);
  }
  __syncthreads();
  float z[4];
  #pragma unroll
  for (int j = 0; j < 4; j++) {
    int d = tid + j * 256; int hh = d >> 6;
    float yn = (ysh[d] - gmean[hh]) * grstd[hh] * gn_g[d] + gn_b[d];
    float gv = Gr[d];
    z[j] = yn * (gv / (1.f + expf(-gv)));            // silu
  }
  float mean = block_sum(z[0] + z[1] + z[2] + z[3], red) * (1.f / DD);
  float var = 0.f;
  #pragma unroll
  for (int j = 0; j < 4; j++) { float dv = z[j] - mean; var += dv * dv; }
  var = block_sum(var, red) * (1.f / DD);
  float rstd = 1.f / sqrtf(var + 1e-5f);
  float ln[4]; float aabs = 0.f;
  #pragma unroll
  for (int j = 0; j < 4; j++) {
    int d = tid + j * 256;
    ln[j] = (z[j] - mean) * rstd * lg[d] + lb[d];
    aabs += fabsf(ln[j]);
  }
  float meanabs = block_sum(aabs, red) * (1.f / DD);
  float scale = fmaxf(meanabs, 1e-8f) * 2.5f * (1.f / 127.f);
  #pragma unroll
  for (int j = 0; j < 4; j++) {
    int d = tid + j * 256;
    xq4[(size_t)m * DD + d] =
        __float2bfloat16(rintf(fminf(fmaxf(ln[j] / scale, -127.f), 127.f)));
  }
  if (tid == 0) ascale4[m] = scale;
}

extern "C" void kernel_launch(void* const* d_in, const int* in_sizes, int n_in,
                              void* d_out, int out_size, void* d_ws, size_t ws_size,
                              hipStream_t stream) {
  // ALL inputs are float32 (verified R4); output float32.
  const float* x         = (const float*)d_in[0];
  const float* mu_r      = (const float*)d_in[1];
  const float* mu_k      = (const float*)d_in[2];
  const float* mu_v      = (const float*)d_in[3];
  const float* mu_g      = (const float*)d_in[4];
  const float* log_decay = (const float*)d_in[5];
  const float* u         = (const float*)d_in[6];
  const float* proj_w    = (const float*)d_in[7];
  const float* ln_g      = (const float*)d_in[8];
  const float* ln_b      = (const float*)d_in[9];
  const float* gn_g      = (const float*)d_in[10];
  const float* gn_b      = (const float*)d_in[11];
  float* out = (float*)d_out;

  // ---- workspace layout, ~234 MiB total; U region (64 MB) time-multiplexed ----
  char* p = (char*)d_ws;
  float*  wscale = (float*)p;  p += 256;                         // 5 f32
  double* wpart  = (double*)p; p += 4096;                        // 5*64 f64
  bf16*   wq     = (bf16*)p;   p += (size_t)5 * DD * DD * 2;     // 10 MB
  float*  ascale = (float*)p;  p += (size_t)5 * M_ROWS * 4;      // 160 KB
  char*   U      = p;          p += (size_t)4 * M_ROWS * DD * 2; // 64 MB
  bf16*   xq     = (bf16*)U;
  float*  Y      = (float*)U;
  bf16*   xq4    = (bf16*)(U + (size_t)M_ROWS * DD * 4);         // U + 32 MB
  float*  rkvg   = (float*)p;  p += (size_t)4 * M_ROWS * DD * 4; // 128 MB
  float*  states = (float*)p;  p += (size_t)BB * HH * NC * SS * SS * 4; // 32 MB

  hipLaunchKernelGGL(k_wscale_part, dim3(5, 64), dim3(256), 0, stream, proj_w, wpart);
  hipLaunchKernelGGL(k_wscale_fin, dim3(5), dim3(64), 0, stream, wpart, wscale);
  hipLaunchKernelGGL(k_wquant, dim3((5 * DD * DD) / 256), dim3(256), 0, stream,
                     proj_w, wscale, wq);
  hipLaunchKernelGGL(k_prep_quant, dim3(M_ROWS, 4), dim3(256), 0, stream,
                     x, mu_r, mu_k, mu_v, mu_g, ln_g, ln_b, xq, ascale);
  hipLaunchKernelGGL(k_gemm, dim3(M_ROWS / 128, DD / 128, 4), dim3(256), 0,
                     stream, xq, wq, ascale, wscale, 0, rkvg);
  hipLaunchKernelGGL(k_inj, dim3(BB * HH * NC), dim3(256), 0, stream,
                     rkvg, log_decay, states);
  hipLaunchKernelGGL(k_scan, dim3(BB * HH), dim3(256), 0, stream, log_decay, states);
  hipLaunchKernelGGL(k_wkv_y, dim3(BB * HH * NC), dim3(256), 0, stream,
                     rkvg, log_decay, u, states, Y);
  hipLaunchKernelGGL(k_post, dim3(M_ROWS), dim3(256), 0, stream,
                     Y, rkvg + (size_t)3 * M_ROWS * DD, gn_g, gn_b,
                     ln_g + 4 * DD, ln_b + 4 * DD,
                     xq4, ascale + 4 * M_ROWS);
  hipLaunchKernelGGL(k_gemm, dim3(M_ROWS / 128, DD / 128, 1), dim3(256), 0,
                     stream, xq4, wq,
                     ascale + 4 * M_ROWS, wscale, 4, out);
}

// Round 7
// 561.716 us; speedup vs baseline: 2.5234x; 2.5234x over previous
//
#include <hip/hip_runtime.h>
#include <hip/hip_bf16.h>

// Problem constants
#define BB 4
#define TT 2048
#define DD 1024
#define HH 16
#define SS 64
#define CH 64
#define NC (TT/CH)        // 32
#define M_ROWS (BB*TT)    // 8192

typedef __hip_bfloat16 bf16;
using short8 = __attribute__((ext_vector_type(8))) short;   // 8 bf16 (4 VGPRs)
using f32x4  = __attribute__((ext_vector_type(4))) float;

static __device__ __forceinline__ float b2f(bf16 v) { return __bfloat162float(v); }

// ---- block-wide sum over 256 threads (deterministic tree) ----
static __device__ __forceinline__ float block_sum(float v, float* red) {
  int tid = threadIdx.x;
  red[tid] = v; __syncthreads();
  #pragma unroll
  for (int o = 128; o > 0; o >>= 1) {
    if (tid < o) red[tid] += red[tid + o];
    __syncthreads();
  }
  float r = red[0];
  __syncthreads();
  return r;
}

// ---- K1a: weight-scale partials. grid (5,64) ----
__global__ __launch_bounds__(256) void k_wscale_part(const float* __restrict__ w,
                                                     double* __restrict__ wpart) {
  __shared__ double red[256];
  int i = blockIdx.x, b = blockIdx.y, tid = threadIdx.x;
  const float* base = w + (size_t)i * DD * DD + (size_t)b * 16384;
  double s = 0.0;
  #pragma unroll
  for (int j = 0; j < 64; j++) s += (double)fabsf(base[tid + j * 256]);
  red[tid] = s; __syncthreads();
  for (int o = 128; o > 0; o >>= 1) {
    if (tid < o) red[tid] += red[tid + o];
    __syncthreads();
  }
  if (tid == 0) wpart[i * 64 + b] = red[0];
}

// ---- K1b: fold 64 partials per matrix in fixed order ----
__global__ __launch_bounds__(64) void k_wscale_fin(const double* __restrict__ wpart,
                                                   float* __restrict__ wscale) {
  int i = blockIdx.x;
  if (threadIdx.x == 0) {
    double s = 0.0;
    for (int b = 0; b < 64; b++) s += wpart[i * 64 + b];
    wscale[i] = fmaxf((float)(s * (1.0 / (DD * DD))), 1e-8f);
  }
}

// ---- K2: ternary weight quant, stored as exact bf16 {-1,0,1} ----
__global__ __launch_bounds__(256) void k_wquant(const float* __restrict__ w,
                                                const float* __restrict__ wscale,
                                                bf16* __restrict__ wq) {
  int idx = blockIdx.x * 256 + threadIdx.x;   // < 5*1024*1024
  int i = idx >> 20;
  float ws = wscale[i];
  float wn = w[idx] / ws;
  wn = fminf(fmaxf(wn, -1.f), 1.f);
  wq[idx] = __float2bfloat16(rintf(wn));
}

// ---- K3: token-shift mix + LayerNorm + activation quant ----
__global__ __launch_bounds__(256) void k_prep_quant(
    const float* __restrict__ x, const float* __restrict__ mu_r,
    const float* __restrict__ mu_k, const float* __restrict__ mu_v,
    const float* __restrict__ mu_g, const float* __restrict__ ln_g,
    const float* __restrict__ ln_b, bf16* __restrict__ xq,
    float* __restrict__ ascale) {
  __shared__ float red[256];
  int m = blockIdx.x, i = blockIdx.y, tid = threadIdx.x;
  int t = m & (TT - 1);
  const float* mu = (i == 0) ? mu_r : (i == 1) ? mu_k : (i == 2) ? mu_v : mu_g;
  const float* xr = x + (size_t)m * DD;
  const float* lg = ln_g + i * DD;
  const float* lb = ln_b + i * DD;
  float inp[4];
  #pragma unroll
  for (int j = 0; j < 4; j++) {
    int d = tid + j * 256;
    float xv = xr[d];
    float xs = (t > 0) ? xr[d - DD] : 0.f;
    inp[j] = xv + (xs - xv) * mu[d];
  }
  float mean = block_sum(inp[0] + inp[1] + inp[2] + inp[3], red) * (1.f / DD);
  float var = 0.f;
  #pragma unroll
  for (int j = 0; j < 4; j++) { float dv = inp[j] - mean; var += dv * dv; }
  var = block_sum(var, red) * (1.f / DD);
  float rstd = 1.f / sqrtf(var + 1e-5f);
  float ln[4]; float aabs = 0.f;
  #pragma unroll
  for (int j = 0; j < 4; j++) {
    int d = tid + j * 256;
    ln[j] = (inp[j] - mean) * rstd * lg[d] + lb[d];
    aabs += fabsf(ln[j]);
  }
  float meanabs = block_sum(aabs, red) * (1.f / DD);
  float scale = fmaxf(meanabs, 1e-8f) * 2.5f * (1.f / 127.f);
  bf16* xo = xq + ((size_t)i * M_ROWS + m) * DD;
  #pragma unroll
  for (int j = 0; j < 4; j++) {
    int d = tid + j * 256;
    float q = rintf(fminf(fmaxf(ln[j] / scale, -127.f), 127.f));
    xo[d] = __float2bfloat16(q);              // exact: |int| <= 127
  }
  if (tid == 0) ascale[i * M_ROWS + m] = scale;
}

// ---- K4/K9: bf16 MFMA GEMM, 128x128 tile (unchanged from R6; validated) ----
__global__ __launch_bounds__(256) void k_gemm(
    const bf16* __restrict__ Axq, const bf16* __restrict__ Wq,
    const float* __restrict__ ascale, const float* __restrict__ wscale,
    int projbase, float* __restrict__ outF) {
  __shared__ short As[128][40];
  __shared__ short Bs[128][40];
  int tid = threadIdx.x;
  int wvid = tid >> 6, lane = tid & 63;
  int wm = wvid >> 1, wn = wvid & 1;
  int m0 = blockIdx.x * 128, n0 = blockIdx.y * 128;
  int z = blockIdx.z;
  int proj = projbase + z;
  const bf16* Ap = Axq + ((size_t)z * M_ROWS + m0) * DD;
  const bf16* Wp = Wq + ((size_t)proj * DD + n0) * DD;
  f32x4 acc[4][4];
  #pragma unroll
  for (int i = 0; i < 4; i++)
    #pragma unroll
    for (int j = 0; j < 4; j++) acc[i][j] = (f32x4){0.f, 0.f, 0.f, 0.f};
  int row = tid >> 2, cg = tid & 3;           // staging: 16B/thread, 2 row-passes
  int frow = lane & 15, fq8 = (lane >> 4) * 8;
  for (int k0 = 0; k0 < DD; k0 += 32) {
    #pragma unroll
    for (int rr = 0; rr < 2; rr++) {
      *(uint4*)&As[rr * 64 + row][cg * 8] =
          *(const uint4*)&Ap[(size_t)(rr * 64 + row) * DD + k0 + cg * 8];
      *(uint4*)&Bs[rr * 64 + row][cg * 8] =
          *(const uint4*)&Wp[(size_t)(rr * 64 + row) * DD + k0 + cg * 8];
    }
    __syncthreads();
    short8 af[4], bfr[4];
    #pragma unroll
    for (int i = 0; i < 4; i++)
      af[i] = *(short8*)&As[64 * wm + 16 * i + frow][fq8];
    #pragma unroll
    for (int j = 0; j < 4; j++)
      bfr[j] = *(short8*)&Bs[64 * wn + 16 * j + frow][fq8];
    #pragma unroll
    for (int i = 0; i < 4; i++)
      #pragma unroll
      for (int j = 0; j < 4; j++)
        acc[i][j] = __builtin_amdgcn_mfma_f32_16x16x32_bf16(af[i], bfr[j], acc[i][j], 0, 0, 0);
    __syncthreads();
  }
  const float* asc = ascale + (size_t)z * M_ROWS + m0;
  float wsc = wscale[proj];
  int col = lane & 15, rg = lane >> 4;
  #pragma unroll
  for (int i = 0; i < 4; i++) {
    #pragma unroll
    for (int r = 0; r < 4; r++) {
      int mm = 64 * wm + 16 * i + rg * 4 + r;
      float s = asc[mm] * wsc;
      #pragma unroll
      for (int j = 0; j < 4; j++) {
        int nn = 64 * wn + 16 * j + col;
        outF[((size_t)z * M_ROWS + m0 + mm) * DD + (n0 + nn)] = acc[i][j][r] * s;
      }
    }
  }
}

// ---- K5: per-chunk injection  inj[s,o] = sum_c w^{63-c} k[c,s] v[c,o] ----
__global__ __launch_bounds__(256) void k_inj(const float* __restrict__ rkvg,
                                             const float* __restrict__ log_decay,
                                             float* __restrict__ states) {
  __shared__ float ksh[CH * SS], vsh[CH * SS];
  int blk = blockIdx.x, tid = threadIdx.x;
  int n = blk & (NC - 1), h = (blk >> 5) & (HH - 1), b = blk >> 9;
  size_t rowbase = ((size_t)b * TT + n * CH) * DD + h * SS;
  const float* Kp = rkvg + (size_t)1 * M_ROWS * DD + rowbase;
  const float* Vp = rkvg + (size_t)2 * M_ROWS * DD + rowbase;
  for (int idx = tid; idx < CH * SS; idx += 256) {
    int c = idx >> 6, s2 = idx & 63;
    ksh[idx] = Kp[(size_t)c * DD + s2];
    vsh[idx] = Vp[(size_t)c * DD + s2];
  }
  int o = tid & 63, sg = tid >> 6;
  float wv[16], acc[16];
  #pragma unroll
  for (int j = 0; j < 16; j++) {
    int s2 = sg * 16 + j;
    float e = expf(log_decay[h * SS + s2]);
    wv[j] = expf(-e); acc[j] = 0.f;
  }
  __syncthreads();
  for (int c = 0; c < CH; c++) {
    float vvv = vsh[c * SS + o];
    #pragma unroll
    for (int j = 0; j < 16; j++)
      acc[j] = wv[j] * acc[j] + ksh[c * SS + sg * 16 + j] * vvv;
  }
  float* st = states + (size_t)blk * SS * SS;
  #pragma unroll
  for (int j = 0; j < 16; j++) st[(size_t)(sg * 16 + j) * SS + o] = acc[j];
}

// ---- K6: in-place scan over chunks ----
__global__ __launch_bounds__(256) void k_scan(const float* __restrict__ log_decay,
                                              float* __restrict__ states) {
  int bh = blockIdx.x, tid = threadIdx.x;
  int h = bh & (HH - 1);
  int o = tid & 63, sg = tid >> 6;
  float wC[16], cur[16];
  #pragma unroll
  for (int j = 0; j < 16; j++) {
    int s2 = sg * 16 + j;
    float e = expf(log_decay[h * SS + s2]);
    wC[j] = expf(-64.f * e);
    cur[j] = 0.f;
  }
  float* base = states + (size_t)bh * NC * SS * SS;
  for (int n = 0; n < NC; n++) {
    float* p = base + (size_t)n * SS * SS;
    #pragma unroll
    for (int j = 0; j < 16; j++) {
      size_t ii = (size_t)(sg * 16 + j) * SS + o;
      float inj = p[ii];
      p[ii] = cur[j];
      cur[j] = wC[j] * cur[j] + inj;
    }
  }
}

// ---- K7 v3: t-tiled WKV. Wave sg owns s-slice [16sg,+16); a[16] scan state
// lives in VGPRs across tiles; y produced 8 t at a time (p[8]) and flushed
// through LDS part -> yacc. Bounded registers (~90), 32 barriers, no spill. ----
#define TTILE 8
__global__ __launch_bounds__(256) void k_wkv_y(const float* __restrict__ rkvg,
                                               const float* __restrict__ log_decay,
                                               const float* __restrict__ u,
                                               const float* __restrict__ states,
                                               float* __restrict__ Y) {
  __shared__ float rsh[CH * SS], ksh[CH * SS], vsh[CH * SS];
  __shared__ float yacc[CH * SS];              // y accumulator (t,o)
  __shared__ float part[TTILE * 4 * SS];       // per-tile per-wave partials
  __shared__ float betash[CH], eush[SS];
  int blk = blockIdx.x, tid = threadIdx.x;
  int n = blk & (NC - 1), h = (blk >> 5) & (HH - 1), b = blk >> 9;
  size_t rowbase = ((size_t)b * TT + n * CH) * DD + h * SS;
  const float* Rp = rkvg + rowbase;
  const float* Kp = rkvg + (size_t)1 * M_ROWS * DD + rowbase;
  const float* Vp = rkvg + (size_t)2 * M_ROWS * DD + rowbase;
  for (int idx = tid; idx < CH * SS; idx += 256) {
    int c = idx >> 6, s2 = idx & 63;
    rsh[idx] = Rp[(size_t)c * DD + s2];
    ksh[idx] = Kp[(size_t)c * DD + s2];
    vsh[idx] = Vp[(size_t)c * DD + s2];
  }
  if (tid < SS) eush[tid] = expf(u[h * SS + tid]);
  __syncthreads();
  // beta[t] = sum_s r[t,s]k[t,s]eu[s]; diagonal access -> conflict-free
  if (tid < CH) {
    float s = 0.f;
    for (int q = 0; q < SS; q++) {
      int s2 = (q + tid) & 63;
      s += rsh[tid * SS + s2] * ksh[tid * SS + s2] * eush[s2];
    }
    betash[tid] = s;
  }
  __syncthreads();

  int o = tid & 63, sg = tid >> 6, S0 = sg * 16;
  float wv[16];
  #pragma unroll
  for (int j = 0; j < 16; j++) wv[j] = expf(-expf(log_decay[h * SS + S0 + j]));

  // reduce-phase mapping: thread handles elements e = tid, tid+256 of (tt,o)
  // ---- pass A: backward suffix scan, tiles of 8 t ----
  float a[16];
  #pragma unroll
  for (int j = 0; j < 16; j++) a[j] = 0.f;
  for (int ti = TTILE - 1; ti >= 0; ti--) {
    float p[TTILE];
    #pragma unroll
    for (int tt = TTILE - 1; tt >= 0; tt--) {
      int t = ti * TTILE + tt;
      float v = vsh[t * SS + o];
      float acc = 0.f;
      #pragma unroll
      for (int q = 0; q < 4; q++) {
        float4 k4 = *(const float4*)&ksh[t * SS + S0 + q * 4];
        float4 r4 = *(const float4*)&rsh[t * SS + S0 + q * 4];
        float kk[4] = {k4.x, k4.y, k4.z, k4.w};
        float rr[4] = {r4.x, r4.y, r4.z, r4.w};
        #pragma unroll
        for (int e = 0; e < 4; e++) {
          int j = q * 4 + e;
          a[j] = fmaf(wv[j], a[j], kk[e] * v);
          acc = fmaf(rr[e], a[j], acc);
        }
      }
      p[tt] = (sg == 0) ? fmaf(betash[t], v, acc) : acc;
    }
    #pragma unroll
    for (int tt = 0; tt < TTILE; tt++) part[tt * 256 + sg * 64 + o] = p[tt];
    __syncthreads();
    #pragma unroll
    for (int rep = 0; rep < 2; rep++) {
      int e = tid + rep * 256;               // 512 elems: (tt,o2)
      int tt = e >> 6, o2 = e & 63;
      float s = part[tt * 256 + o2] + part[tt * 256 + 64 + o2]
              + part[tt * 256 + 128 + o2] + part[tt * 256 + 192 + o2];
      yacc[(ti * TTILE + tt) * SS + o2] = s;
    }
    __syncthreads();
  }
  // ---- pass B: forward cross-chunk term, tiles of 8 t ----
  const float* stp = states + (size_t)blk * SS * SS;
  float st[16], pw[16];
  #pragma unroll
  for (int j = 0; j < 16; j++) {
    st[j] = stp[(size_t)(S0 + j) * SS + o] ;
    pw[j] = wv[j];                            // w^{t+1} at t=0
  }
  for (int ti = 0; ti < TTILE; ti++) {
    float p[TTILE];
    #pragma unroll
    for (int tt = 0; tt < TTILE; tt++) {
      int t = ti * TTILE + tt;
      float acc = 0.f;
      #pragma unroll
      for (int q = 0; q < 4; q++) {
        float4 r4 = *(const float4*)&rsh[t * SS + S0 + q * 4];
        float rr[4] = {r4.x, r4.y, r4.z, r4.w};
        #pragma unroll
        for (int e = 0; e < 4; e++) {
          int j = q * 4 + e;
          acc = fmaf(rr[e], pw[j] * st[j], acc);
          pw[j] *= wv[j];
        }
      }
      p[tt] = acc;
    }
    #pragma unroll
    for (int tt = 0; tt < TTILE; tt++) part[tt * 256 + sg * 64 + o] = p[tt];
    __syncthreads();
    #pragma unroll
    for (int rep = 0; rep < 2; rep++) {
      int e = tid + rep * 256;
      int tt = e >> 6, o2 = e & 63;
      float s = part[tt * 256 + o2] + part[tt * 256 + 64 + o2]
              + part[tt * 256 + 128 + o2] + part[tt * 256 + 192 + o2];
      yacc[(ti * TTILE + tt) * SS + o2] += s;
    }
    __syncthreads();
  }
  // ---- final coalesced write ----
  float* Yb = Y + ((size_t)b * TT + n * CH) * DD + h * SS;
  #pragma unroll
  for (int it = 0; it < 16; it++) {
    int idx = tid + it * 256;                 // (t, o)
    int t = idx >> 6, o2 = idx & 63;
    Yb[(size_t)t * DD + o2] = yacc[idx];
  }
}

// ---- K8: GroupNorm + silu(g) + LayerNorm + act-quant ----
__global__ __launch_bounds__(256) void k_post(const float* __restrict__ Y,
                                              const float* __restrict__ G,
                                              const float* __restrict__ gn_g,
                                              const float* __restrict__ gn_b,
                                              const float* __restrict__ lg,
                                              const float* __restrict__ lb,
                                              bf16* __restrict__ xq4,
                                              float* __restrict__ ascale4) {
  __shared__ float red[256];
  __shared__ float ysh[DD];
  __shared__ float gmean[HH], grstd[HH];
  int m = blockIdx.x, tid = threadIdx.x;
  const float* Yr = Y + (size_t)m * DD;
  const float* Gr = G + (size_t)m * DD;
  #pragma unroll
  for (int j = 0; j < 4; j++) { int d = tid + j * 256; ysh[d] = Yr[d]; }
  __syncthreads();
  if (tid < HH) {
    float s = 0.f;
    for (int q2 = 0; q2 < SS; q2++) s += ysh[tid * SS + ((q2 + tid * 4) & 63)];
    float mn = s * (1.f / SS);
    float v2 = 0.f;
    for (int q2 = 0; q2 < SS; q2++) {
      float dv = ysh[tid * SS + ((q2 + tid * 4) & 63)] - mn; v2 += dv * dv;
    }
    gmean[tid] = mn;
    grstd[tid] = 1.f / sqrtf(v2 * (1.f / SS) + 1e-5f);
  }
  __syncthreads();
  float z[4];
  #pragma unroll
  for (int j = 0; j < 4; j++) {
    int d = tid + j * 256; int hh = d >> 6;
    float yn = (ysh[d] - gmean[hh]) * grstd[hh] * gn_g[d] + gn_b[d];
    float gv = Gr[d];
    z[j] = yn * (gv / (1.f + expf(-gv)));            // silu
  }
  float mean = block_sum(z[0] + z[1] + z[2] + z[3], red) * (1.f / DD);
  float var = 0.f;
  #pragma unroll
  for (int j = 0; j < 4; j++) { float dv = z[j] - mean; var += dv * dv; }
  var = block_sum(var, red) * (1.f / DD);
  float rstd = 1.f / sqrtf(var + 1e-5f);
  float ln[4]; float aabs = 0.f;
  #pragma unroll
  for (int j = 0; j < 4; j++) {
    int d = tid + j * 256;
    ln[j] = (z[j] - mean) * rstd * lg[d] + lb[d];
    aabs += fabsf(ln[j]);
  }
  float meanabs = block_sum(aabs, red) * (1.f / DD);
  float scale = fmaxf(meanabs, 1e-8f) * 2.5f * (1.f / 127.f);
  #pragma unroll
  for (int j = 0; j < 4; j++) {
    int d = tid + j * 256;
    xq4[(size_t)m * DD + d] =
        __float2bfloat16(rintf(fminf(fmaxf(ln[j] / scale, -127.f), 127.f)));
  }
  if (tid == 0) ascale4[m] = scale;
}

extern "C" void kernel_launch(void* const* d_in, const int* in_sizes, int n_in,
                              void* d_out, int out_size, void* d_ws, size_t ws_size,
                              hipStream_t stream) {
  // ALL inputs are float32 (verified R4); output float32.
  const float* x         = (const float*)d_in[0];
  const float* mu_r      = (const float*)d_in[1];
  const float* mu_k      = (const float*)d_in[2];
  const float* mu_v      = (const float*)d_in[3];
  const float* mu_g      = (const float*)d_in[4];
  const float* log_decay = (const float*)d_in[5];
  const float* u         = (const float*)d_in[6];
  const float* proj_w    = (const float*)d_in[7];
  const float* ln_g      = (const float*)d_in[8];
  const float* ln_b      = (const float*)d_in[9];
  const float* gn_g      = (const float*)d_in[10];
  const float* gn_b      = (const float*)d_in[11];
  float* out = (float*)d_out;

  // ---- workspace layout, ~234 MiB total; U region (64 MB) time-multiplexed ----
  char* p = (char*)d_ws;
  float*  wscale = (float*)p;  p += 256;                         // 5 f32
  double* wpart  = (double*)p; p += 4096;                        // 5*64 f64
  bf16*   wq     = (bf16*)p;   p += (size_t)5 * DD * DD * 2;     // 10 MB
  float*  ascale = (float*)p;  p += (size_t)5 * M_ROWS * 4;      // 160 KB
  char*   U      = p;          p += (size_t)4 * M_ROWS * DD * 2; // 64 MB
  bf16*   xq     = (bf16*)U;
  float*  Y      = (float*)U;
  bf16*   xq4    = (bf16*)(U + (size_t)M_ROWS * DD * 4);         // U + 32 MB
  float*  rkvg   = (float*)p;  p += (size_t)4 * M_ROWS * DD * 4; // 128 MB
  float*  states = (float*)p;  p += (size_t)BB * HH * NC * SS * SS * 4; // 32 MB

  hipLaunchKernelGGL(k_wscale_part, dim3(5, 64), dim3(256), 0, stream, proj_w, wpart);
  hipLaunchKernelGGL(k_wscale_fin, dim3(5), dim3(64), 0, stream, wpart, wscale);
  hipLaunchKernelGGL(k_wquant, dim3((5 * DD * DD) / 256), dim3(256), 0, stream,
                     proj_w, wscale, wq);
  hipLaunchKernelGGL(k_prep_quant, dim3(M_ROWS, 4), dim3(256), 0, stream,
                     x, mu_r, mu_k, mu_v, mu_g, ln_g, ln_b, xq, ascale);
  hipLaunchKernelGGL(k_gemm, dim3(M_ROWS / 128, DD / 128, 4), dim3(256), 0,
                     stream, xq, wq, ascale, wscale, 0, rkvg);
  hipLaunchKernelGGL(k_inj, dim3(BB * HH * NC), dim3(256), 0, stream,
                     rkvg, log_decay, states);
  hipLaunchKernelGGL(k_scan, dim3(BB * HH), dim3(256), 0, stream, log_decay, states);
  hipLaunchKernelGGL(k_wkv_y, dim3(BB * HH * NC), dim3(256), 0, stream,
                     rkvg, log_decay, u, states, Y);
  hipLaunchKernelGGL(k_post, dim3(M_ROWS), dim3(256), 0, stream,
                     Y, rkvg + (size_t)3 * M_ROWS * DD, gn_g, gn_b,
                     ln_g + 4 * DD, ln_b + 4 * DD,
                     xq4, ascale + 4 * M_ROWS);
  hipLaunchKernelGGL(k_gemm, dim3(M_ROWS / 128, DD / 128, 1), dim3(256), 0,
                     stream, xq4, wq,
                     ascale + 4 * M_ROWS, wscale, 4, out);
}